// Round 1
// baseline (1998.144 us; speedup 1.0000x reference)
//
#include <hip/hip_runtime.h>
#include <hip/hip_bf16.h>

typedef _Float16 f16x8 __attribute__((ext_vector_type(8)));
typedef float f32x4 __attribute__((ext_vector_type(4)));

namespace {
constexpr int N_ = 100000;
constexpr int E_ = 400000;
constexpr int D_ = 256;
constexpr int L_ = 3;
constexpr int R_ = 4;
constexpr int G_ = 2000;
constexpr int NRXN_ = 10;
constexpr int CTXW = L_*D_ + D_ + L_*D_ + NRXN_;   // 1802
constexpr int GCTXW = L_*D_ + NRXN_;               // 778
constexpr int NKT = (R_+1)*D_/32;                  // 40 k-tiles of 32
constexpr int NB1 = (N_ + 1023)/1024;              // 98 scan blocks
}

// ---------- small utility kernels ----------

__global__ void k_zero(int* __restrict__ p, int n) {
  int i = blockIdx.x*256 + threadIdx.x;
  if (i < n) p[i] = 0;
}

// sniff center_mask dtype: 0=int32, 1=float32, 2=byte(bool)
__global__ void k_detect(const unsigned char* __restrict__ cm, int* __restrict__ meta) {
  int tid = threadIdx.x;
  int ok_i = 1, ok_f = 1;
  for (int i = tid; i < 4096; i += 256) {
    unsigned b = cm[i];
    int m = i & 3;
    if (m == 0)      { if (b > 1) ok_i = 0; if (b != 0) ok_f = 0; }
    else if (m == 1) { if (b) { ok_i = 0; ok_f = 0; } }
    else if (m == 2) { if (b) ok_i = 0; if (b != 0 && b != 0x80) ok_f = 0; }
    else             { if (b) ok_i = 0; if (b != 0 && b != 0x3f) ok_f = 0; }
  }
  int all_i = __syncthreads_and(ok_i);
  int all_f = __syncthreads_and(ok_f);
  if (tid == 0) meta[0] = all_i ? 0 : (all_f ? 1 : 2);
}

__global__ void k_hist(const int* __restrict__ key, int* __restrict__ hist, int n) {
  int i = blockIdx.x*256 + threadIdx.x;
  if (i < n) atomicAdd(&hist[key[i]], 1);
}

__global__ void k_scan1(const int* __restrict__ h, int* __restrict__ out,
                        int* __restrict__ bsum, int n) {
  __shared__ int sh[256];
  int t = threadIdx.x;
  int base = blockIdx.x*1024 + t*4;
  int v0 = (base+0 < n) ? h[base+0] : 0;
  int v1 = (base+1 < n) ? h[base+1] : 0;
  int v2 = (base+2 < n) ? h[base+2] : 0;
  int v3 = (base+3 < n) ? h[base+3] : 0;
  int s = v0+v1+v2+v3;
  sh[t] = s; __syncthreads();
  for (int off = 1; off < 256; off <<= 1) {
    int x = (t >= off) ? sh[t-off] : 0;
    __syncthreads();
    sh[t] += x;
    __syncthreads();
  }
  int ex = sh[t] - s;
  if (base+0 < n) out[base+0] = ex; ex += v0;
  if (base+1 < n) out[base+1] = ex; ex += v1;
  if (base+2 < n) out[base+2] = ex; ex += v2;
  if (base+3 < n) out[base+3] = ex;
  if (t == 255) bsum[blockIdx.x] = sh[255];
}

__global__ void k_scan2(int* __restrict__ b, int nb) {
  __shared__ int sh[256];
  int t = threadIdx.x;
  int s = (t < nb) ? b[t] : 0;
  sh[t] = s; __syncthreads();
  for (int off = 1; off < 256; off <<= 1) {
    int x = (t >= off) ? sh[t-off] : 0;
    __syncthreads();
    sh[t] += x;
    __syncthreads();
  }
  if (t < nb) b[t] = sh[t] - s;
}

__global__ void k_scan3(int* __restrict__ eoff, const int* __restrict__ bsum,
                        int* __restrict__ cursor, int n, int total) {
  int i = blockIdx.x*256 + threadIdx.x;
  if (i < n) {
    int v = eoff[i] + bsum[i >> 10];
    eoff[i] = v;
    cursor[i] = v;
  }
  if (i == 0) eoff[n] = total;
}

__global__ void k_scatter(const int* __restrict__ src, const int* __restrict__ dst,
                          const int* __restrict__ typ, int* __restrict__ cursor,
                          unsigned* __restrict__ out, int n) {
  int i = blockIdx.x*256 + threadIdx.x;
  if (i < n) {
    int d = dst[i];
    int p = atomicAdd(&cursor[d], 1);
    out[p] = (unsigned)src[i] | ((unsigned)typ[i] << 24);
  }
}

__global__ void k_scan_small(const int* __restrict__ gh, int* __restrict__ goff, int g) {
  __shared__ int sh[256];
  int t = threadIdx.x;
  int v[8]; int s = 0;
  #pragma unroll
  for (int j = 0; j < 8; ++j) { int idx = t*8+j; v[j] = (idx < g) ? gh[idx] : 0; s += v[j]; }
  sh[t] = s; __syncthreads();
  for (int off = 1; off < 256; off <<= 1) {
    int x = (t >= off) ? sh[t-off] : 0;
    __syncthreads();
    sh[t] += x;
    __syncthreads();
  }
  int ex = sh[t] - s;
  #pragma unroll
  for (int j = 0; j < 8; ++j) { int idx = t*8+j; if (idx < g) goff[idx] = ex; ex += v[j]; }
  if (t == 255) goff[g] = sh[255];
}

// pack W into MFMA B-fragment layout: Bp[((l*NKT+kt)*16+ct)*64+lane][j] =
//   B[k = kt*32 + (lane>>4)*8 + j][col = ct*16 + (lane&15)]
// where B = [W_rel[l] (1024 x 256, natural layout) ; W_self[l] (256 x 256)]
__global__ void k_pack_w(const float* __restrict__ Wrel, const float* __restrict__ Wself,
                         f16x8* __restrict__ Bp) {
  int id = blockIdx.x*256 + threadIdx.x;
  if (id >= L_*NKT*16*64) return;
  int lane = id & 63; int rest = id >> 6;
  int ct = rest & 15; rest >>= 4;
  int kt = rest % NKT; int l = rest / NKT;
  int q = lane >> 4, ln = lane & 15;
  int col = ct*16 + ln;
  f16x8 o;
  #pragma unroll
  for (int j = 0; j < 8; ++j) {
    int k = kt*32 + q*8 + j;
    float v = (k < R_*D_) ? Wrel[((size_t)l*R_*D_ + k)*D_ + col]
                          : Wself[((size_t)l*D_ + (k - R_*D_))*D_ + col];
    o[j] = (_Float16)v;
  }
  Bp[id] = o;
}

// x0 = node_feature + mask*flag_W[1] + flag_b  (f16); also copy node_feature to out cols [768:1024)
__global__ void k_node_init(const float* __restrict__ nf, const float* __restrict__ fW,
                            const float* __restrict__ fb, const void* __restrict__ cm,
                            const int* __restrict__ meta, _Float16* __restrict__ xa,
                            float* __restrict__ out) {
  int n = blockIdx.x, c = threadIdx.x;
  float v = nf[(size_t)n*D_ + c];
  out[(size_t)n*CTXW + 768 + c] = v;
  int mode = meta[0];
  bool mk;
  if (mode == 0)      mk = ((const int*)cm)[n] != 0;
  else if (mode == 1) mk = ((const float*)cm)[n] != 0.f;
  else                mk = ((const unsigned char*)cm)[n] != 0;
  float x0 = v + (mk ? fW[D_ + c] : 0.f) + fb[c];
  xa[(size_t)n*D_ + c] = (_Float16)x0;
}

// ---------- fused RGCN layer ----------
// block = 256 thr (4 waves), M-tile = 64 nodes. Wave w owns output cols [w*64, w*64+64).
// K = 1280: 4 relation phases (gather->LDS fp32 accumulate -> MFMA) + self phase.
// LDS As: [64 rows][64 granules of 16B], granule XOR-swizzled by (row&7) -> conflict-free b128.
__global__ __launch_bounds__(256, 2)
void k_layer(const _Float16* __restrict__ xin, const f16x8* __restrict__ Bp,
             const float* __restrict__ bias, const int* __restrict__ eoff,
             const unsigned* __restrict__ edges, float* __restrict__ outp,
             _Float16* __restrict__ xout) {
  __shared__ f32x4 As4[64*64];
  __shared__ float invdeg[64];
  const int tid = threadIdx.x;
  const int lane = tid & 63, wave = tid >> 6;
  const int q = lane >> 4, ln = lane & 15;
  const int m0 = blockIdx.x * 64;

  if (wave == 0) {
    int n = m0 + lane;
    int c = (n < N_) ? (eoff[n+1] - eoff[n]) : 0;
    invdeg[lane] = 1.0f / (float)(c > 1 ? c : 1);
  }

  f32x4 acc[4][4];
  #pragma unroll
  for (int rt = 0; rt < 4; ++rt)
    #pragma unroll
    for (int cc = 0; cc < 4; ++cc)
      acc[rt][cc] = f32x4{0.f,0.f,0.f,0.f};

  // ---- self phase: A = xin rows directly (k in [1024,1280)) ----
  {
    int rb[4];
    #pragma unroll
    for (int rt = 0; rt < 4; ++rt) {
      int row = m0 + rt*16 + ln;
      rb[rt] = (row < N_ ? row : N_-1) * D_;
    }
    #pragma unroll
    for (int kt = 0; kt < 8; ++kt) {
      f16x8 a[4], b[4];
      #pragma unroll
      for (int rt = 0; rt < 4; ++rt)
        a[rt] = *(const f16x8*)(xin + rb[rt] + kt*32 + q*8);
      #pragma unroll
      for (int cc = 0; cc < 4; ++cc)
        b[cc] = Bp[(size_t)((32 + kt)*16 + wave*4 + cc)*64 + lane];
      #pragma unroll
      for (int rt = 0; rt < 4; ++rt)
        #pragma unroll
        for (int cc = 0; cc < 4; ++cc)
          acc[rt][cc] = __builtin_amdgcn_mfma_f32_16x16x32_f16(a[rt], b[cc], acc[rt][cc], 0,0,0);
    }
  }
  __syncthreads();

  const int n = m0 + lane;
  const int ebeg = (n < N_) ? eoff[n] : 0;
  const int eend = (n < N_) ? eoff[n+1] : 0;
  const int sw = lane & 7;
  const int gb = lane * 64;

  for (int r = 0; r < R_; ++r) {
    for (int i = tid; i < 64*64; i += 256) As4[i] = f32x4{0.f,0.f,0.f,0.f};
    __syncthreads();
    // gather: lane owns dst row `lane`, wave owns col chunk [wave*64, wave*64+64)
    for (int e = ebeg; e < eend; ++e) {
      unsigned p = edges[e];
      if ((int)(p >> 24) == r) {
        const f16x8* srow = (const f16x8*)(xin + (size_t)(p & 0x00FFFFFFu) * D_ + wave*64);
        #pragma unroll
        for (int j = 0; j < 8; ++j) {
          f16x8 v = srow[j];
          f32x4 lo = {(float)v[0], (float)v[1], (float)v[2], (float)v[3]};
          f32x4 hi = {(float)v[4], (float)v[5], (float)v[6], (float)v[7]};
          int g0 = wave*16 + 2*j;
          As4[gb + ((g0  ) ^ sw)] += lo;
          As4[gb + ((g0+1) ^ sw)] += hi;
        }
      }
    }
    __syncthreads();
    float sc[4]; int rl[4];
    #pragma unroll
    for (int rt = 0; rt < 4; ++rt) { rl[rt] = rt*16 + ln; sc[rt] = invdeg[rl[rt]]; }
    #pragma unroll
    for (int kt = 0; kt < 8; ++kt) {
      f16x8 a[4], b[4];
      #pragma unroll
      for (int rt = 0; rt < 4; ++rt) {
        int g0 = kt*8 + q*2;
        int swr = rl[rt] & 7;
        f32x4 lo = As4[rl[rt]*64 + ((g0  ) ^ swr)];
        f32x4 hi = As4[rl[rt]*64 + ((g0+1) ^ swr)];
        float s = sc[rt];
        f16x8 av;
        av[0] = (_Float16)(lo[0]*s); av[1] = (_Float16)(lo[1]*s);
        av[2] = (_Float16)(lo[2]*s); av[3] = (_Float16)(lo[3]*s);
        av[4] = (_Float16)(hi[0]*s); av[5] = (_Float16)(hi[1]*s);
        av[6] = (_Float16)(hi[2]*s); av[7] = (_Float16)(hi[3]*s);
        a[rt] = av;
      }
      #pragma unroll
      for (int cc = 0; cc < 4; ++cc)
        b[cc] = Bp[(size_t)((r*8 + kt)*16 + wave*4 + cc)*64 + lane];
      #pragma unroll
      for (int rt = 0; rt < 4; ++rt)
        #pragma unroll
        for (int cc = 0; cc < 4; ++cc)
          acc[rt][cc] = __builtin_amdgcn_mfma_f32_16x16x32_f16(a[rt], b[cc], acc[rt][cc], 0,0,0);
    }
    __syncthreads();
  }

  // epilogue: +bias, relu, write strided fp32 to out, compact f16 to xout
  #pragma unroll
  for (int cc = 0; cc < 4; ++cc) {
    int col = (wave*4 + cc)*16 + ln;
    float bv = bias[col];
    #pragma unroll
    for (int rt = 0; rt < 4; ++rt) {
      #pragma unroll
      for (int i = 0; i < 4; ++i) {
        int row = m0 + rt*16 + q*4 + i;
        if (row < N_) {
          float v = acc[rt][cc][i] + bv;
          v = fmaxf(v, 0.f);
          outp[(size_t)row*CTXW + col] = v;
          if (xout) xout[(size_t)row*D_ + col] = (_Float16)v;
        }
      }
    }
  }
}

// segment-mean over sorted batch; one block per graph
__global__ void k_pool(float* __restrict__ out, const int* __restrict__ goff,
                       const int* __restrict__ rxn) {
  int g = blockIdx.x, t = threadIdx.x;
  int s = goff[g], e = goff[g+1];
  int cnt = e - s;
  float inv = 1.0f / (float)(cnt > 1 ? cnt : 1);
  float a0 = 0.f, a1 = 0.f, a2 = 0.f;
  for (int nn = s; nn < e; ++nn) {
    size_t base = (size_t)nn*CTXW;
    a0 += out[base + t];
    a1 += out[base + 256 + t];
    a2 += out[base + 512 + t];
  }
  size_t gbase = (size_t)N_*CTXW + (size_t)g*GCTXW;
  out[gbase + t]       = a0*inv;
  out[gbase + 256 + t] = a1*inv;
  out[gbase + 512 + t] = a2*inv;
  if (t < NRXN_) out[gbase + 768 + t] = (rxn[g] == t) ? 1.f : 0.f;
}

// node_context cols [1024,1802) = graph_context[batch[n]]
__global__ void k_bcast(float* __restrict__ out, const int* __restrict__ batch) {
  int nn = blockIdx.x, t = threadIdx.x;
  size_t gbase = (size_t)N_*CTXW + (size_t)batch[nn]*GCTXW;
  size_t nb = (size_t)nn*CTXW + 1024;
  out[nb + t]       = out[gbase + t];
  out[nb + 256 + t] = out[gbase + 256 + t];
  out[nb + 512 + t] = out[gbase + 512 + t];
  if (t < GCTXW - 768) out[nb + 768 + t] = out[gbase + 768 + t];
}

extern "C" void kernel_launch(void* const* d_in, const int* in_sizes, int n_in,
                              void* d_out, int out_size, void* d_ws, size_t ws_size,
                              hipStream_t stream) {
  const float* node_feature = (const float*)d_in[0];
  const float* flag_W  = (const float*)d_in[1];
  const float* flag_b  = (const float*)d_in[2];
  const float* W_self  = (const float*)d_in[3];
  const float* b_self  = (const float*)d_in[4];
  const float* W_rel   = (const float*)d_in[5];
  const int* edge_src  = (const int*)d_in[6];
  const int* edge_dst  = (const int*)d_in[7];
  const int* edge_type = (const int*)d_in[8];
  const int* batch     = (const int*)d_in[9];
  const int* reaction  = (const int*)d_in[10];
  const void* cmask    = d_in[11];
  float* out = (float*)d_out;

  char* ws = (char*)d_ws;
  size_t off = 0;
  auto alloc = [&](size_t bytes) {
    void* p = ws + off;
    off = (off + bytes + 255) & ~(size_t)255;
    return p;
  };
  int* meta          = (int*)alloc(256);
  _Float16* xa       = (_Float16*)alloc((size_t)N_*D_*2);
  _Float16* xb       = (_Float16*)alloc((size_t)N_*D_*2);
  f16x8* Bp          = (f16x8*)alloc((size_t)L_*NKT*16*64*16);
  int* eoff          = (int*)alloc((size_t)(N_+1)*4);
  int* cursor        = (int*)alloc((size_t)N_*4);
  int* ghist         = (int*)alloc((size_t)G_*4);
  int* goff          = (int*)alloc((size_t)(G_+1)*4);
  int* bsum          = (int*)alloc(1024);
  unsigned* esorted  = (unsigned*)alloc((size_t)E_*4);
  (void)in_sizes; (void)n_in; (void)out_size; (void)ws_size;

  k_detect<<<1, 256, 0, stream>>>((const unsigned char*)cmask, meta);
  k_zero<<<(N_+255)/256, 256, 0, stream>>>(cursor, N_);
  k_zero<<<(G_+255)/256, 256, 0, stream>>>(ghist, G_);
  k_hist<<<(E_+255)/256, 256, 0, stream>>>(edge_dst, cursor, E_);
  k_scan1<<<NB1, 256, 0, stream>>>(cursor, eoff, bsum, N_);
  k_scan2<<<1, 256, 0, stream>>>(bsum, NB1);
  k_scan3<<<(N_+255)/256, 256, 0, stream>>>(eoff, bsum, cursor, N_, E_);
  k_scatter<<<(E_+255)/256, 256, 0, stream>>>(edge_src, edge_dst, edge_type, cursor, esorted, E_);
  k_hist<<<(N_+255)/256, 256, 0, stream>>>(batch, ghist, N_);
  k_scan_small<<<1, 256, 0, stream>>>(ghist, goff, G_);
  k_pack_w<<<(L_*NKT*16*64 + 255)/256, 256, 0, stream>>>(W_rel, W_self, Bp);
  k_node_init<<<N_, 256, 0, stream>>>(node_feature, flag_W, flag_b, cmask, meta, xa, out);

  const int nblk = (N_ + 63)/64;
  k_layer<<<nblk, 256, 0, stream>>>(xa, Bp,          b_self,       eoff, esorted, out,       xb);
  k_layer<<<nblk, 256, 0, stream>>>(xb, Bp + 40960,  b_self + 256, eoff, esorted, out + 256, xa);
  k_layer<<<nblk, 256, 0, stream>>>(xa, Bp + 81920,  b_self + 512, eoff, esorted, out + 512, nullptr);

  k_pool<<<G_, 256, 0, stream>>>(out, goff, reaction);
  k_bcast<<<N_, 256, 0, stream>>>(out, batch);
}